// Round 1
// baseline (153.826 us; speedup 1.0000x reference)
//
#include <hip/hip_runtime.h>
#include <hip/hip_bf16.h>

typedef __bf16 bf16_t;
typedef __bf16 bf16x4 __attribute__((ext_vector_type(4)));
typedef __bf16 bf16x8 __attribute__((ext_vector_type(8)));
typedef float f32x4 __attribute__((ext_vector_type(4)));

#define ALPHA 8.3f
#define CPAD 72   // bf16 channel stride (144 B, 16B-aligned)
#define NCOL 68   // staged cols (64-q tile + halo + align)

// img: [4][64][256][256] f32, depth: [4][1][256][256] f32,
// weight: [64][64][3][3] f32, bias: [1][64] f32, out: [4][64][254][254] f32

// Repack weight -> bf16 A-fragment order [tap(9)][chunk(2)][mblock(4)][lane(64)][j(8)]
__global__ void repack_w(const float* __restrict__ w, bf16_t* __restrict__ w2) {
    int idx = blockIdx.x * 256 + threadIdx.x;  // 0..36863
    if (idx >= 9 * 2 * 4 * 64 * 8) return;
    int j     = idx & 7;
    int lane  = (idx >> 3) & 63;
    int m     = (idx >> 9) & 3;
    int chunk = (idx >> 11) & 1;
    int tap   = idx >> 12;
    int oc = m * 16 + (lane & 15);
    int c  = chunk * 32 + (lane >> 4) * 8 + j;
    int kt = tap / 3, lt = tap % 3;
    w2[idx] = (bf16_t)w[((oc * 64 + c) * 3 + kt) * 3 + lt];
}

// Block = 256 thr (4 waves) = (2 p-rows) x (2 oc-halves) per pair, 2 pairs per block.
// 4-slot LDS row ring: stage rows p0..p0+3, prefetch p0+4/p0+5 into regs BEFORE
// pair-0 compute (loads fly under the MFMAs), write them over slots 0,1 after the
// barrier, compute pair 1 from slots 2,3,0,1.  6 staged rows / 4 output rows.
// 64 strips x 16 (b,qt) = 1024 blocks = exactly 4 blocks/CU, one resident cohort.
__global__ __launch_bounds__(256, 2) void depthconv_mfma(
    const float* __restrict__ img, const float* __restrict__ depth,
    const bf16_t* __restrict__ w2, const float* __restrict__ bias,
    float* __restrict__ out)
{
    __shared__ bf16_t lds[4 * NCOL * CPAD];  // 39,168 B -> 4 blocks/CU by LDS

    const int tid   = threadIdx.x;
    const int blk   = blockIdx.x;
    const int strip = blk >> 4;              // 0..63, 4 output rows each
    const int r     = blk & 15;              // (b,qt) stream -> stays on one XCD
    const int b     = r >> 2;
    const int qt    = r & 3;
    const int p0    = (strip == 63) ? 250 : strip * 4;  // rows 250/251 dup-written identically
    const int q0    = (qt == 3) ? 190 : qt * 64;        // q 190/191 dup-written identically
    const int s0    = (qt == 3) ? 188 : q0;

    const float* imgb = img + (size_t)b * 64 * 65536;
    const float* dep  = depth + (size_t)b * 65536;

    // ---- prologue: stage img rows p0..p0+3 -> slots 0..3 (f32 -> bf16 transpose) ----
#pragma unroll
    for (int k = 0; k < 5; ++k) {
        int u = tid + (k << 8);
        if (u < 1088) {
            int cg   = u & 15;
            int rest = u >> 4;        // 0..67
            int colg = rest % 17;
            int row  = rest / 17;
            const float* src = imgb + (size_t)(cg * 4) * 65536 + (p0 + row) * 256 + s0 + colg * 4;
            f32x4 v0 = *(const f32x4*)src;
            f32x4 v1 = *(const f32x4*)(src + 65536);
            f32x4 v2 = *(const f32x4*)(src + 2 * 65536);
            f32x4 v3 = *(const f32x4*)(src + 3 * 65536);
            bf16_t* dst = lds + (size_t)(row * NCOL + colg * 4) * CPAD + cg * 4;
#pragma unroll
            for (int i = 0; i < 4; ++i)
                *(bf16x4*)(dst + i * CPAD) =
                    (bf16x4){(bf16_t)v0[i], (bf16_t)v1[i], (bf16_t)v2[i], (bf16_t)v3[i]};
        }
    }
    __syncthreads();

    // ---- prefetch rows p0+4, p0+5 (cols 0..63) into registers; consumed after pair 0.
    // unit: (cg = tid&15, colg = tid>>4 in 0..15), both rows per thread: 8 x f32x4 = 32 VGPR.
    const int pcg   = tid & 15;
    const int pcolg = tid >> 4;
    const float* psrc = imgb + (size_t)(pcg * 4) * 65536 + (p0 + 4) * 256 + s0 + pcolg * 4;
    f32x4 pf[4][2];   // [channel][row]
#pragma unroll
    for (int ch = 0; ch < 4; ++ch)
#pragma unroll
        for (int rw = 0; rw < 2; ++rw)
            pf[ch][rw] = *(const f32x4*)(psrc + (size_t)ch * 65536 + rw * 256);

    const int wv   = tid >> 6;
    const int lane = tid & 63;
    const int pr   = wv >> 1;          // p-row within pair
    const int mh   = wv & 1;           // oc-half (mblocks 2mh, 2mh+1)
    const int n    = lane & 15;
    const int quad = lane >> 4;
    const int clb0 = q0 - s0;

    const f32x4 Z = (f32x4){0.f, 0.f, 0.f, 0.f};

#pragma unroll
    for (int t = 0; t < 2; ++t) {
        const int prow = p0 + 2 * t + pr;
        const int sb   = 2 * t;        // ring slot base: row (p0+j) lives in slot j&3

        float dc[4];
#pragma unroll
        for (int i = 0; i < 4; ++i)
            dc[i] = dep[(prow + 1) * 256 + q0 + 16 * i + n + 1];

        f32x4 acc[2][4];
#pragma unroll
        for (int mm = 0; mm < 2; ++mm)
#pragma unroll
            for (int i = 0; i < 4; ++i) acc[mm][i] = Z;

#pragma unroll
        for (int kt = 0; kt < 3; ++kt) {
            const int slot = (sb + pr + kt) & 3;
            float dwv[3][4];
#pragma unroll
            for (int lt = 0; lt < 3; ++lt)
#pragma unroll
                for (int i = 0; i < 4; ++i) {
                    float d = dep[(prow + kt) * 256 + q0 + 16 * i + n + lt];
                    dwv[lt][i] = __expf(-ALPHA * fabsf(d - dc[i]));
                }
#pragma unroll
            for (int lt = 0; lt < 3; ++lt) {
                const int tap = kt * 3 + lt;
                const bf16x8* w2p = (const bf16x8*)w2 + ((size_t)(tap * 2) * 4 + mh * 2) * 64 + lane;
                bf16x8 a00 = w2p[0];           // chunk0, mm0
                bf16x8 a01 = w2p[64];          // chunk0, mm1
                bf16x8 a10 = w2p[256];         // chunk1, mm0
                bf16x8 a11 = w2p[256 + 64];    // chunk1, mm1
#pragma unroll
                for (int i = 0; i < 4; ++i) {
                    const bf16_t* lp = lds
                        + (size_t)(slot * NCOL + clb0 + 16 * i + n + lt) * CPAD + quad * 8;
                    const bf16x8 bf0 = *(const bf16x8*)lp;
                    const bf16x8 bf1 = *(const bf16x8*)(lp + 32);
                    f32x4 P0 = __builtin_amdgcn_mfma_f32_16x16x32_bf16(a00, bf0, Z, 0, 0, 0);
                    f32x4 P1 = __builtin_amdgcn_mfma_f32_16x16x32_bf16(a01, bf0, Z, 0, 0, 0);
                    P0 = __builtin_amdgcn_mfma_f32_16x16x32_bf16(a10, bf1, P0, 0, 0, 0);
                    P1 = __builtin_amdgcn_mfma_f32_16x16x32_bf16(a11, bf1, P1, 0, 0, 0);
                    acc[0][i] += dwv[lt][i] * P0;
                    acc[1][i] += dwv[lt][i] * P1;
                }
            }
        }

        // epilogue: D[row=quad*4+r2][col=n]; oc = (mh*2+mm)*16 + quad*4 + r2
#pragma unroll
        for (int mm = 0; mm < 2; ++mm) {
#pragma unroll
            for (int r2 = 0; r2 < 4; ++r2) {
                int oc = (mh * 2 + mm) * 16 + quad * 4 + r2;
                float bz = bias[oc];
#pragma unroll
                for (int i = 0; i < 4; ++i) {
                    int q = q0 + 16 * i + n;
                    out[((size_t)(b * 64 + oc) * 254 + prow) * 254 + q] = acc[mm][i][r2] + bz;
                }
            }
        }

        if (t == 0) {
            __syncthreads();   // slots 0,1 reads done; pf loads drained by barrier's vmcnt(0)

            // tail: cols 64..67 of rows p0+4/p0+5 (32 threads); latency hides under writes
            f32x4 tl[4];
            const int trw = tid >> 4;
            const float* tsrc = imgb + (size_t)(pcg * 4) * 65536 + (p0 + 4 + trw) * 256 + s0 + 64;
            if (tid < 32) {
#pragma unroll
                for (int ch = 0; ch < 4; ++ch)
                    tl[ch] = *(const f32x4*)(tsrc + (size_t)ch * 65536);
            }

            // write prefetched rows p0+4 -> slot 0, p0+5 -> slot 1
#pragma unroll
            for (int rw = 0; rw < 2; ++rw) {
                bf16_t* dst = lds + (size_t)(rw * NCOL + pcolg * 4) * CPAD + pcg * 4;
#pragma unroll
                for (int i = 0; i < 4; ++i)
                    *(bf16x4*)(dst + i * CPAD) =
                        (bf16x4){(bf16_t)pf[0][rw][i], (bf16_t)pf[1][rw][i],
                                 (bf16_t)pf[2][rw][i], (bf16_t)pf[3][rw][i]};
            }
            if (tid < 32) {
                bf16_t* dst = lds + (size_t)(trw * NCOL + 64) * CPAD + pcg * 4;
#pragma unroll
                for (int i = 0; i < 4; ++i)
                    *(bf16x4*)(dst + i * CPAD) =
                        (bf16x4){(bf16_t)tl[0][i], (bf16_t)tl[1][i],
                                 (bf16_t)tl[2][i], (bf16_t)tl[3][i]};
            }
            __syncthreads();
        }
    }
}

extern "C" void kernel_launch(void* const* d_in, const int* in_sizes, int n_in,
                              void* d_out, int out_size, void* d_ws, size_t ws_size,
                              hipStream_t stream) {
    const float* img   = (const float*)d_in[0];
    const float* depth = (const float*)d_in[1];
    const float* w     = (const float*)d_in[2];
    const float* bias  = (const float*)d_in[3];
    bf16_t* w2 = (bf16_t*)d_ws;

    repack_w<<<144, 256, 0, stream>>>(w, w2);
    // 64 p-strips x 4 b x 4 q-tiles = 1024 blocks, 256 thr (4 waves)
    depthconv_mfma<<<1024, 256, 0, stream>>>(img, depth, w2, bias, (float*)d_out);
}